// Round 1
// baseline (223.757 us; speedup 1.0000x reference)
//
#include <hip/hip_runtime.h>

// out[b,d,n] = w[d] * in[b,d,n]; B=8, D=2048, N=2048, fp32.
// Memory-bound elementwise scale. One thread per float4 (16B/lane coalesced).
// Each N-row = 512 float4s -> channel d of float4 i is (i >> 9) & (D-1),
// wave-uniform across a 64-lane wave (wave spans 256 floats < 2048-row).

__global__ __launch_bounds__(256) void channel_scale_kernel(
    const float4* __restrict__ in, const float* __restrict__ w,
    float4* __restrict__ out, int total4) {
    int i = blockIdx.x * blockDim.x + threadIdx.x;
    if (i >= total4) return;
    int d = (i >> 9) & 2047;   // (i*4 / N) % D with N=2048, D=2048
    float s = w[d];
    float4 v = in[i];
    v.x *= s; v.y *= s; v.z *= s; v.w *= s;
    out[i] = v;
}

extern "C" void kernel_launch(void* const* d_in, const int* in_sizes, int n_in,
                              void* d_out, int out_size, void* d_ws, size_t ws_size,
                              hipStream_t stream) {
    const float4* in = (const float4*)d_in[0];
    const float*  w  = (const float*)d_in[1];
    float4* out = (float4*)d_out;
    int total4 = out_size / 4;                 // 33,554,432 / 4 = 8,388,608
    int blocks = (total4 + 255) / 256;         // 32,768 blocks
    channel_scale_kernel<<<blocks, 256, 0, stream>>>(in, w, out, total4);
}

// Round 3
// 220.567 us; speedup vs baseline: 1.0145x; 1.0145x over previous
//
#include <hip/hip_runtime.h>

// out[b,d,n] = w[d] * in[b,d,n]; B=8, D=2048, N=2048, fp32.
// Pure streaming scale: 268 MB R+W, roofline ~43 us at 6.3-6.7 TB/s measured.
// One block per N-row (2048 floats): 256 threads x 2 float4 (16B/lane x2).
// Row index == blockIdx.x -> d = blockIdx.x % D is BLOCK-UNIFORM -> scalar
// weight load. Nontemporal ld/st (native clang vector type -- HIP float4 is
// a struct the builtin rejects): streaming data (268 MB >> 32 MB L2).

typedef float floatx4 __attribute__((ext_vector_type(4)));

__global__ __launch_bounds__(256) void channel_scale_kernel(
    const floatx4* __restrict__ in, const float* __restrict__ w,
    floatx4* __restrict__ out) {
    const int row = blockIdx.x;            // in [0, B*D)
    const float s = w[row & 2047];         // d = row % D, uniform per block
    const long base = (long)row * 512;     // 512 float4s per row
    const int t = threadIdx.x;

    floatx4 v0 = __builtin_nontemporal_load(&in[base + t]);
    floatx4 v1 = __builtin_nontemporal_load(&in[base + t + 256]);
    v0 *= s;
    v1 *= s;
    __builtin_nontemporal_store(v0, &out[base + t]);
    __builtin_nontemporal_store(v1, &out[base + t + 256]);
}

extern "C" void kernel_launch(void* const* d_in, const int* in_sizes, int n_in,
                              void* d_out, int out_size, void* d_ws, size_t ws_size,
                              hipStream_t stream) {
    const floatx4* in = (const floatx4*)d_in[0];
    const float*   w  = (const float*)d_in[1];
    floatx4* out = (floatx4*)d_out;
    int rows = out_size / 2048;            // B*D = 16384 blocks, one row each
    channel_scale_kernel<<<rows, 256, 0, stream>>>(in, w, out);
}